// Round 9
// baseline (717.794 us; speedup 1.0000x reference)
//
#include <hip/hip_runtime.h>
#include <hip/hip_bf16.h>
#include <cstdio>
#include <cmath>

// Problem constants (B,T,C,NH fixed by the reference)
constexpr int   Bn = 4;
constexpr int   Tn = 2048;
constexpr int   Cn = 768;
constexpr float COEF  = 0.125f / 12.0f;   // SCALE / NH
constexpr float EPSZ  = 1e-8f;
constexpr float LNEPS = 1e-5f;
constexpr int   NTRI  = 136;              // triangular 128-tiles per batch
#define NBTC ((size_t)Bn * Tn * Cn)

typedef __bf16 bf16_t;
typedef _Float16 f16_t;
typedef bf16_t bf16x8 __attribute__((ext_vector_type(8)));
typedef f16_t  f16x8  __attribute__((ext_vector_type(8)));
typedef float  f32x4  __attribute__((ext_vector_type(4)));
typedef ushort u16x8  __attribute__((ext_vector_type(8)));

// async global->LDS, 16B per lane. LDS dest is wave-uniform base + lane*16.
__device__ __forceinline__ void gload16(const void* g, void* l) {
  __builtin_amdgcn_global_load_lds(
      (const __attribute__((address_space(1))) unsigned int*)g,
      (__attribute__((address_space(3))) unsigned int*)l,
      16, 0, 0);
}

__device__ __forceinline__ ushort bf16_bits(float f) {
  bf16_t h = (bf16_t)f;
  return __builtin_bit_cast(ushort, h);
}
__device__ __forceinline__ float bits_to_f(ushort u) {
  return (float)__builtin_bit_cast(bf16_t, u);
}

// cst[] indices: 0 Lam_tk, 1 lam_tk, 2 Lam_tbar, 3 lam_tbar, 4 Lam_tk1, 5 lam_tk1, 6 = 1.0
__global__ void prep_consts(const int* kp, float* cst) {
  if (threadIdx.x == 0 && blockIdx.x == 0) {
    float tk = 1.0f + (float)(*kp);
    float tb = tk + 0.5f;
    float t1 = tk + 1.0f;
    cst[0] = tk * tk * tk; cst[1] = 1.0f / cst[0];
    cst[2] = tb * tb * tb; cst[3] = 1.0f / cst[2];
    cst[4] = t1 * t1 * t1; cst[5] = 1.0f / cst[4];
    cst[6] = 1.0f;
  }
}

// LayerNorm of (alpha*src) -> fp16 (gram) + bf16 (corepass) outputs, PLUS
// |Pi row|^2 reduction -> aab[row] (raw, ps applied later in svfin).
// Also zeroes zbuf[row] for zpass atomics.
__global__ void __launch_bounds__(256) ln_sv_kernel(
    const float* __restrict__ src, const float* __restrict__ w,
    f16_t* __restrict__ outF, bf16_t* __restrict__ outB,
    float* __restrict__ zbuf, float* __restrict__ aab,
    const float* __restrict__ Pisrc,
    const float* __restrict__ cst, int alpha_idx) {
  const int row = blockIdx.x;
  const int tid = threadIdx.x;
  const float alpha = cst[alpha_idx];
  const float* x = src + (size_t)row * Cn;
  float v0 = alpha * x[tid];
  float v1 = alpha * x[tid + 256];
  float v2 = alpha * x[tid + 512];
  __shared__ float red[256];
  red[tid] = v0 + v1 + v2;
  __syncthreads();
  for (int off = 128; off > 0; off >>= 1) {
    if (tid < off) red[tid] += red[tid + off];
    __syncthreads();
  }
  const float m = red[0] * (1.0f / Cn);
  __syncthreads();
  const float d0 = v0 - m, d1 = v1 - m, d2 = v2 - m;
  red[tid] = d0 * d0 + d1 * d1 + d2 * d2;
  __syncthreads();
  for (int off = 128; off > 0; off >>= 1) {
    if (tid < off) red[tid] += red[tid + off];
    __syncthreads();
  }
  const float rstd = rsqrtf(red[0] * (1.0f / Cn) + LNEPS);
  const size_t base = (size_t)row * Cn;
  float f0 = d0 * rstd * w[tid];
  float f1 = d1 * rstd * w[tid + 256];
  float f2 = d2 * rstd * w[tid + 512];
  outF[base + tid]       = (f16_t)f0;  outB[base + tid]       = (bf16_t)f0;
  outF[base + tid + 256] = (f16_t)f1;  outB[base + tid + 256] = (bf16_t)f1;
  outF[base + tid + 512] = (f16_t)f2;  outB[base + tid + 512] = (bf16_t)f2;

  // |p|^2 reduction of the Pi-side row
  const float* p = Pisrc + base;
  const float p0 = p[tid], p1 = p[tid + 256], p2 = p[tid + 512];
  __syncthreads();
  red[tid] = p0 * p0 + p1 * p1 + p2 * p2;
  __syncthreads();
  for (int off = 128; off > 0; off >>= 1) {
    if (tid < off) red[tid] += red[tid + off];
    __syncthreads();
  }
  if (tid == 0) {
    aab[row] = red[0];
    zbuf[row] = 0.0f;
  }
}

// Transpose Xnb [b][s][c] -> XT [b][c][s] (bf16). grid (Tn/64, Cn/64, Bn).
__global__ void __launch_bounds__(256) xt_kernel(
    const ushort* __restrict__ Xh, ushort* __restrict__ XT) {
  const int b = blockIdx.z;
  const int s0 = blockIdx.x * 64, c0 = blockIdx.y * 64;
  const int tid = threadIdx.x;
  __shared__ ushort t[64][68];
  const ushort* src = Xh + (size_t)b * Tn * Cn;
  ushort* dst = XT + (size_t)b * Cn * Tn;
  #pragma unroll
  for (int p = 0; p < 4; ++p) {
    const int r = p * 16 + (tid >> 4);
    const int c = (tid & 15) * 4;
    const ushort4 v = *(const ushort4*)&src[(size_t)(s0 + r) * Cn + c0 + c];
    *(ushort4*)&t[r][c] = v;
  }
  __syncthreads();
  #pragma unroll
  for (int p = 0; p < 4; ++p) {
    const int cc = p * 16 + (tid >> 4);
    const int ss = (tid & 15) * 4;
    ushort4 o;
    o.x = t[ss + 0][cc]; o.y = t[ss + 1][cc];
    o.z = t[ss + 2][cc]; o.w = t[ss + 3][cc];
    *(ushort4*)&dst[(size_t)(c0 + cc) * Tn + s0 + ss] = o;
  }
}

// Causal gram, 128x64 tile, single-fp16 MFMA, K=64 double-slab chunks.
// E = exp(clip(S*COEF)) stored single-bf16 into packed 128x128 triangular
// tiles (pair-packed uint stores). Row sums -> atomicAdd zbuf.
// grid = (272, Bn), block 256.
__global__ void __launch_bounds__(256) zpass_mfma(
    const f16_t* __restrict__ XnF,
    ushort* __restrict__ Ehp, float* __restrict__ zbuf) {
  const int b = blockIdx.y;
  const int l = blockIdx.x;
  int it = (int)(0.5f * (sqrtf(4.0f * (float)l + 1.0f) - 1.0f));
  while ((it + 1) * (it + 2) <= l) ++it;
  while (it * (it + 1) > l) --it;
  const int js = l - it * (it + 1);          // 0 .. 2it+1
  const int t0 = it * 128, s0 = js * 64;
  const int tri = it * (it + 1) / 2 + (js >> 1);
  const int colTileBase = (js & 1) * 64;

  const int tid  = threadIdx.x;
  const int lane = tid & 63;
  const int wv   = tid >> 6;
  const int wr   = wv >> 1, wc = wv & 1;     // wave covers 64t x 32s
  const int quad = lane >> 4, l15 = lane & 15;

  const f16_t* XbF = XnF + (size_t)b * Tn * Cn;
  ushort* EhT = Ehp + ((size_t)b * NTRI + tri) * 16384;

  __shared__ f16_t Af[2][128 * 32];   // 16 KB
  __shared__ f16_t Bf[2][64 * 32];    // 8 KB

  const int srow = lane >> 2;                // 0..15
  const int scol = (lane & 3) * 8;

  f32x4 acc[4][2] = {};

  for (int c0 = 0; c0 < Cn; c0 += 64) {
    __syncthreads();                 // protect LDS while prev chunk still read
    #pragma unroll
    for (int h = 0; h < 2; ++h) {
      const int cb = c0 + h * 32;
      const int rb0 = wv * 16, rb1 = 64 + wv * 16;
      gload16(XbF + (size_t)(t0 + rb0 + srow) * Cn + cb + scol, Af[h] + rb0 * 32);
      gload16(XbF + (size_t)(t0 + rb1 + srow) * Cn + cb + scol, Af[h] + rb1 * 32);
      gload16(XbF + (size_t)(s0 + rb0 + srow) * Cn + cb + scol, Bf[h] + rb0 * 32);
    }
    __syncthreads();                 // drain vmcnt + all slabs present

    #pragma unroll
    for (int h = 0; h < 2; ++h) {
      f16x8 af[4], bf[2];
      #pragma unroll
      for (int i = 0; i < 4; ++i)
        af[i] = *(const f16x8*)&Af[h][(wr * 64 + i * 16 + l15) * 32 + quad * 8];
      #pragma unroll
      for (int j = 0; j < 2; ++j)
        bf[j] = *(const f16x8*)&Bf[h][(wc * 32 + j * 16 + l15) * 32 + quad * 8];
      #pragma unroll
      for (int i = 0; i < 4; ++i)
        #pragma unroll
        for (int j = 0; j < 2; ++j)
          acc[i][j] = __builtin_amdgcn_mfma_f32_16x16x32_f16(af[i], bf[j], acc[i][j], 0, 0, 0);
    }
  }

  float zacc[4][4];
  #pragma unroll
  for (int i = 0; i < 4; ++i)
    #pragma unroll
    for (int r = 0; r < 4; ++r) zacc[i][r] = 0.0f;

  #pragma unroll
  for (int i = 0; i < 4; ++i) {
    #pragma unroll
    for (int j = 0; j < 2; ++j) {
      const int inCol = colTileBase + wc * 32 + j * 16 + l15;
      const int gcol  = s0 + wc * 32 + j * 16 + l15;
      #pragma unroll
      for (int r = 0; r < 4; ++r) {
        const int rowL = wr * 64 + i * 16 + quad * 4 + r;
        float sV = acc[i][j][r] * COEF;
        sV = fminf(fmaxf(sV, -60.f), 60.f);
        const float e = (gcol <= t0 + rowL) ? __expf(sV) : 0.f;
        const float pe = __shfl_xor(e, 1);
        if ((lane & 1) == 0) {
          const uint pk = (uint)bf16_bits(e) | ((uint)bf16_bits(pe) << 16);
          *(uint*)&EhT[rowL * 128 + inCol] = pk;
        }
        zacc[i][r] += e;
      }
    }
  }
  #pragma unroll
  for (int i = 0; i < 4; ++i)
    #pragma unroll
    for (int r = 0; r < 4; ++r) {
      float v = zacc[i][r];
      v += __shfl_xor(v, 1);
      v += __shfl_xor(v, 2);
      v += __shfl_xor(v, 4);
      v += __shfl_xor(v, 8);
      if (l15 == 0)
        atomicAdd(&zbuf[b * Tn + t0 + wr * 64 + i * 16 + quad * 4 + r], v);
    }
}

// Finalize z and sv elementwise over all Bn*Tn rows.
// zf = max(zsum/T, EPS); sv = aab*ps^2 / (zf^2 + EPS).
__global__ void __launch_bounds__(256) svfin_kernel(
    float* __restrict__ zbuf, float* __restrict__ sv,
    const float* __restrict__ aab, const float* __restrict__ cst, int ps_idx) {
  const int i = blockIdx.x * 256 + threadIdx.x;
  const float ps = cst[ps_idx];
  const float zf = fmaxf(zbuf[i] * (1.0f / Tn), EPSZ);
  zbuf[i] = zf;
  sv[i] = aab[i] * ps * ps / (zf * zf + EPSZ);
}

// core GEMM + in-register W-build + fused elementwise epilogues.
// W[t][s] = bf16( f32(E[t][s]) * (sv[t]-2+sv[s]) )  -- identical numerics to
// the old wbuild pass. dst = src*cst[ss_idx] + coef * W @ Xn, then per MODE.
// Tile 128t x 64c; 1D grid of 768 blocks, XCD-affinity swizzled so the 12
// c-blocks sharing an E strip land on the same XCD (id % 8 residue).
template <int MODE>
__global__ void __launch_bounds__(256) corepass_mfma(
    const ushort* __restrict__ Ehp, const ushort* __restrict__ XT,
    const float* __restrict__ sv,
    const float* src, float* dst,
    const float* __restrict__ cst, int ss_idx, int lam_idx,
    float* eA, float* eB, float* eC, float* eD,
    const float* __restrict__ zb, int vel_idx, float rc, float rs) {
  // decode: id = r8 + 8*(g>>3) + 64*ic, g = (it<<2)|b
  const int id = blockIdx.x;
  const int r8 = id & 7;
  const int m  = id >> 3;
  const int g  = ((m & 7) << 3) | r8;
  const int ic = m >> 3;                 // 0..11
  const int it = g >> 2;                 // 0..15
  const int b  = g & 3;                  // 0..3
  const int t0 = it * 128, c0 = ic * 64;

  const int tid  = threadIdx.x;
  const int lane = tid & 63;
  const int wv   = tid >> 6;
  const int wr   = wv >> 1, wc = wv & 1;   // wave covers 64t x 32c
  const int quad = lane >> 4, l15 = lane & 15;

  const ushort* EhB = Ehp + (size_t)b * NTRI * 16384;
  const ushort* XTb = XT + (size_t)b * Cn * Tn;
  const float*  svB = sv + b * Tn;

  __shared__ ushort Ah[2][128 * 32];   // E slabs  (16 KB)
  __shared__ ushort Bh[2][64 * 32];    // X^T slabs (8 KB)

  const int srow = lane >> 2;
  const int scol = (lane & 3) * 8;
  const int triBase = it * (it + 1) / 2;

  float svt2[4];
  #pragma unroll
  for (int i = 0; i < 4; ++i)
    svt2[i] = svB[t0 + wr * 64 + i * 16 + l15] - 2.0f;

  f32x4 acc[4][2] = {};
  const int chunks = (it + 1) * 2;           // 64-k chunks
  for (int kc = 0; kc < chunks; ++kc) {
    const int ss0 = kc * 64;
    const int stile = kc >> 1, soff = (kc & 1) * 64;
    const ushort* tileB = EhB + (size_t)(triBase + stile) * 16384 + soff;

    __syncthreads();                 // prev chunk's LDS reads done
    #pragma unroll
    for (int h = 0; h < 2; ++h) {
      const ushort* tileH = tileB + h * 32;
      const int rb0 = wv * 16, rb1 = 64 + wv * 16;
      gload16(tileH + (size_t)(rb0 + srow) * 128 + scol, Ah[h] + rb0 * 32);
      gload16(tileH + (size_t)(rb1 + srow) * 128 + scol, Ah[h] + rb1 * 32);
      gload16(XTb + (size_t)(c0 + wv * 16 + srow) * Tn + ss0 + h * 32 + scol,
              Bh[h] + wv * 16 * 32);
    }
    __syncthreads();                 // drain vmcnt

    #pragma unroll
    for (int h = 0; h < 2; ++h) {
      // per-quad sv[s] vector for this 32-half
      const float4 sa = *(const float4*)(svB + ss0 + h * 32 + quad * 8);
      const float4 sb = *(const float4*)(svB + ss0 + h * 32 + quad * 8 + 4);
      const float svs[8] = {sa.x, sa.y, sa.z, sa.w, sb.x, sb.y, sb.z, sb.w};
      bf16x8 ah[4], bh[2];
      #pragma unroll
      for (int i = 0; i < 4; ++i) {
        const u16x8 er = *(const u16x8*)&Ah[h][(wr * 64 + i * 16 + l15) * 32 + quad * 8];
        #pragma unroll
        for (int q = 0; q < 8; ++q)
          ah[i][q] = (bf16_t)(bits_to_f(er[q]) * (svt2[i] + svs[q]));
      }
      #pragma unroll
      for (int j = 0; j < 2; ++j)
        bh[j] = *(const bf16x8*)&Bh[h][(wc * 32 + j * 16 + l15) * 32 + quad * 8];
      #pragma unroll
      for (int i = 0; i < 4; ++i)
        #pragma unroll
        for (int j = 0; j < 2; ++j)
          acc[i][j] = __builtin_amdgcn_mfma_f32_16x16x32_bf16(ah[i], bh[j], acc[i][j], 0, 0, 0);
    }
  }

  const float coef = 0.5f * cst[lam_idx] * (1.0f / (2.0f * Tn));
  const float ssc = cst[ss_idx];
  const float vs = 0.5f * cst[vel_idx];
  #pragma unroll
  for (int i = 0; i < 4; ++i) {
    #pragma unroll
    for (int j = 0; j < 2; ++j) {
      const int col = c0 + wc * 32 + j * 16 + l15;
      #pragma unroll
      for (int r = 0; r < 4; ++r) {
        const int row = t0 + wr * 64 + i * 16 + quad * 4 + r;
        const size_t off = ((size_t)b * Tn + row) * Cn + col;
        const float srcv = src[off];
        const float d = srcv * ssc + coef * acc[i][j][r];
        if (MODE == 0) {
          dst[off] = d;
          eC[off] = eA[off] + vs * srcv / zb[b * Tn + row];
        } else if (MODE == 1) {
          const float z  = zb[b * Tn + row];
          const float po = eB[off];
          const float xo = eA[off] + vs * po / z;
          const float bx = eC[off];
          const float dX = xo - bx, dPi = po - d;
          const float sX = xo + bx, sPi = po + d;
          eD[off]  = 0.5f * (sX + rc * dX + rs * dPi);   // Xo
          eB[off]  = 0.5f * (sPi - rs * dX + rc * dPi);  // Po
          eC[off]  = 0.5f * (sX - rc * dX - rs * dPi);   // bX
          dst[off] = 0.5f * (sPi + rs * dX - rc * dPi);  // bPi
        } else if (MODE == 2) {
          dst[off] = d;
          eA[off] = eA[off] + vs * eB[off] / zb[b * Tn + row];
        } else {
          dst[off] = d;
        }
      }
    }
  }
}

// Final LayerNorm (fp32 out, in-place capable)
__global__ void __launch_bounds__(256) ln_f32_kernel(
    const float* src, const float* __restrict__ w,
    float* dst, const float* __restrict__ cst, int alpha_idx) {
  const int row = blockIdx.x;
  const int tid = threadIdx.x;
  const float alpha = cst[alpha_idx];
  const float* x = src + (size_t)row * Cn;
  float v0 = alpha * x[tid];
  float v1 = alpha * x[tid + 256];
  float v2 = alpha * x[tid + 512];
  __shared__ float red[256];
  red[tid] = v0 + v1 + v2;
  __syncthreads();
  for (int off = 128; off > 0; off >>= 1) {
    if (tid < off) red[tid] += red[tid + off];
    __syncthreads();
  }
  const float m = red[0] * (1.0f / Cn);
  __syncthreads();
  const float d0 = v0 - m, d1 = v1 - m, d2 = v2 - m;
  red[tid] = d0 * d0 + d1 * d1 + d2 * d2;
  __syncthreads();
  for (int off = 128; off > 0; off >>= 1) {
    if (tid < off) red[tid] += red[tid + off];
    __syncthreads();
  }
  const float rstd = rsqrtf(red[0] * (1.0f / Cn) + LNEPS);
  float* y = dst + (size_t)row * Cn;
  y[tid]       = d0 * rstd * w[tid];
  y[tid + 256] = d1 * rstd * w[tid + 256];
  y[tid + 512] = d2 * rstd * w[tid + 512];
}

extern "C" void kernel_launch(void* const* d_in, const int* in_sizes, int n_in,
                              void* d_out, int out_size, void* d_ws, size_t ws_size,
                              hipStream_t stream) {
  (void)in_sizes; (void)n_in; (void)out_size;
  const float* Xk  = (const float*)d_in[0];
  const float* Pk  = (const float*)d_in[1];
  const float* lw  = (const float*)d_in[2];
  const float* lvw = (const float*)d_in[3];
  const int*   kp  = (const int*)d_in[4];

  float* Xo = (float*)d_out;        // X state in d_out[0:BTC]
  float* Po = Xo + NBTC;            // Pi state in d_out[BTC:2BTC]

  char* wp = (char*)d_ws;
  float*  bX  = (float*)wp;  wp += NBTC * sizeof(float);
  float*  bPi = (float*)wp;  wp += NBTC * sizeof(float);
  f16_t*  XnF = (f16_t*)wp;  wp += NBTC * sizeof(f16_t);
  bf16_t* Xnb = (bf16_t*)wp; wp += NBTC * sizeof(bf16_t);
  ushort* Ehp = (ushort*)wp; wp += (size_t)Bn * NTRI * 16384 * sizeof(ushort);
  ushort* XTh = (ushort*)wp; wp += NBTC * sizeof(ushort);
  float*  zb  = (float*)wp;  wp += (size_t)Bn * Tn * sizeof(float);
  float*  sv  = (float*)wp;  wp += (size_t)Bn * Tn * sizeof(float);
  float*  aab = (float*)wp;  wp += (size_t)Bn * Tn * sizeof(float);
  float*  cst = (float*)wp;  wp += 256;
  const size_t need = (size_t)(wp - (char*)d_ws);
  if (ws_size < need) {
    fprintf(stderr, "[kernel] ws too small: %zu < %zu\n", ws_size, need);
    return;
  }

  const dim3 b256(256);
  const dim3 gLN(Bn * Tn);
  const dim3 gXT(Tn / 64, Cn / 64, Bn);      // (32,12,4)
  const dim3 gZ(272, Bn);                    // causal 128x64 tiles x batch
  const dim3 gSV(Bn * Tn / 256);             // 32 blocks
  const dim3 gCore(768);                     // XCD-swizzled 1D grid
  const float rc = (float)cos(2.0), rs = (float)sin(2.0);   // theta = 2*XI*h

  prep_consts<<<1, 1, 0, stream>>>(kp, cst);

  // ---- Stage A: X-side = Xk, p = Pk (lam*Lam = 1) ----
  ln_sv_kernel<<<gLN, b256, 0, stream>>>(Xk, lw, XnF, Xnb, zb, aab, Pk, cst, 6);
  xt_kernel<<<gXT, b256, 0, stream>>>((const ushort*)Xnb, XTh);
  zpass_mfma<<<gZ, b256, 0, stream>>>(XnF, Ehp, zb);
  svfin_kernel<<<gSV, b256, 0, stream>>>(zb, sv, aab, cst, 6);
  corepass_mfma<0><<<gCore, b256, 0, stream>>>(Ehp, XTh, sv, Pk, Po, cst, 0, 0,
      (float*)Xk, nullptr, bX, nullptr, zb, 6, rc, rs);

  // ---- Stage B: X-side = bX, Pi-side = Po; fused velupd-B + rotation ----
  ln_sv_kernel<<<gLN, b256, 0, stream>>>(bX, lw, XnF, Xnb, zb, aab, Po, cst, 6);
  xt_kernel<<<gXT, b256, 0, stream>>>((const ushort*)Xnb, XTh);
  zpass_mfma<<<gZ, b256, 0, stream>>>(XnF, Ehp, zb);
  svfin_kernel<<<gSV, b256, 0, stream>>>(zb, sv, aab, cst, 3);
  corepass_mfma<1><<<gCore, b256, 0, stream>>>(Ehp, XTh, sv, Pk, bPi, cst, 0, 2,
      (float*)Xk, Po, bX, Xo, zb, 3, rc, rs);

  // ---- Stage C: X-side = bX, Pi-side = Po; fused velupd-C ----
  ln_sv_kernel<<<gLN, b256, 0, stream>>>(bX, lw, XnF, Xnb, zb, aab, Po, cst, 6);
  xt_kernel<<<gXT, b256, 0, stream>>>((const ushort*)Xnb, XTh);
  zpass_mfma<<<gZ, b256, 0, stream>>>(XnF, Ehp, zb);
  svfin_kernel<<<gSV, b256, 0, stream>>>(zb, sv, aab, cst, 3);
  corepass_mfma<2><<<gCore, b256, 0, stream>>>(Ehp, XTh, sv, bPi, bPi, cst, 6, 2,
      Xo, Po, nullptr, nullptr, zb, 3, rc, rs);

  // ---- Stage D: X-side = Xo, p = lam_tk1*bPi ----
  ln_sv_kernel<<<gLN, b256, 0, stream>>>(Xo, lw, XnF, Xnb, zb, aab, bPi, cst, 6);
  xt_kernel<<<gXT, b256, 0, stream>>>((const ushort*)Xnb, XTh);
  zpass_mfma<<<gZ, b256, 0, stream>>>(XnF, Ehp, zb);
  svfin_kernel<<<gSV, b256, 0, stream>>>(zb, sv, aab, cst, 5);
  corepass_mfma<3><<<gCore, b256, 0, stream>>>(Ehp, XTh, sv, Po, Po, cst, 6, 4,
      nullptr, nullptr, nullptr, nullptr, zb, 6, rc, rs);

  // ---- Final: Pk1 = LN(lam_tk1 * Pi) * ln_v_w (in place on Po) ----
  ln_f32_kernel<<<gLN, b256, 0, stream>>>(Po, lvw, Po, cst, 5);
}

// Round 10
// 692.735 us; speedup vs baseline: 1.0362x; 1.0362x over previous
//
#include <hip/hip_runtime.h>
#include <hip/hip_bf16.h>
#include <cstdio>
#include <cmath>

// Problem constants (B,T,C,NH fixed by the reference)
constexpr int   Bn = 4;
constexpr int   Tn = 2048;
constexpr int   Cn = 768;
constexpr float COEF  = 0.125f / 12.0f;   // SCALE / NH
constexpr float EPSZ  = 1e-8f;
constexpr float LNEPS = 1e-5f;
constexpr int   NTRI  = 136;              // triangular 128-tiles per batch
#define NBTC ((size_t)Bn * Tn * Cn)

typedef __bf16 bf16_t;
typedef _Float16 f16_t;
typedef bf16_t bf16x8 __attribute__((ext_vector_type(8)));
typedef f16_t  f16x8  __attribute__((ext_vector_type(8)));
typedef float  f32x4  __attribute__((ext_vector_type(4)));
typedef ushort u16x8  __attribute__((ext_vector_type(8)));

// async global->LDS, 16B per lane. LDS dest is wave-uniform base + lane*16.
__device__ __forceinline__ void gload16(const void* g, void* l) {
  __builtin_amdgcn_global_load_lds(
      (const __attribute__((address_space(1))) unsigned int*)g,
      (__attribute__((address_space(3))) unsigned int*)l,
      16, 0, 0);
}

__device__ __forceinline__ ushort bf16_bits(float f) {
  bf16_t h = (bf16_t)f;
  return __builtin_bit_cast(ushort, h);
}
__device__ __forceinline__ float bits_to_f(ushort u) {
  return (float)__builtin_bit_cast(bf16_t, u);
}

// cst[] indices: 0 Lam_tk, 1 lam_tk, 2 Lam_tbar, 3 lam_tbar, 4 Lam_tk1, 5 lam_tk1, 6 = 1.0
__global__ void prep_consts(const int* kp, float* cst) {
  if (threadIdx.x == 0 && blockIdx.x == 0) {
    float tk = 1.0f + (float)(*kp);
    float tb = tk + 0.5f;
    float t1 = tk + 1.0f;
    cst[0] = tk * tk * tk; cst[1] = 1.0f / cst[0];
    cst[2] = tb * tb * tb; cst[3] = 1.0f / cst[2];
    cst[4] = t1 * t1 * t1; cst[5] = 1.0f / cst[4];
    cst[6] = 1.0f;
  }
}

// LayerNorm of (alpha*src) -> fp16 (gram) + bf16 (corepass) outputs, PLUS
// |Pi row|^2 reduction -> aab[row]. Also zeroes zbuf[row] for zpass atomics.
__global__ void __launch_bounds__(256) ln_sv_kernel(
    const float* __restrict__ src, const float* __restrict__ w,
    f16_t* __restrict__ outF, bf16_t* __restrict__ outB,
    float* __restrict__ zbuf, float* __restrict__ aab,
    const float* __restrict__ Pisrc,
    const float* __restrict__ cst, int alpha_idx) {
  const int row = blockIdx.x;
  const int tid = threadIdx.x;
  const float alpha = cst[alpha_idx];
  const float* x = src + (size_t)row * Cn;
  float v0 = alpha * x[tid];
  float v1 = alpha * x[tid + 256];
  float v2 = alpha * x[tid + 512];
  __shared__ float red[256];
  red[tid] = v0 + v1 + v2;
  __syncthreads();
  for (int off = 128; off > 0; off >>= 1) {
    if (tid < off) red[tid] += red[tid + off];
    __syncthreads();
  }
  const float m = red[0] * (1.0f / Cn);
  __syncthreads();
  const float d0 = v0 - m, d1 = v1 - m, d2 = v2 - m;
  red[tid] = d0 * d0 + d1 * d1 + d2 * d2;
  __syncthreads();
  for (int off = 128; off > 0; off >>= 1) {
    if (tid < off) red[tid] += red[tid + off];
    __syncthreads();
  }
  const float rstd = rsqrtf(red[0] * (1.0f / Cn) + LNEPS);
  const size_t base = (size_t)row * Cn;
  float f0 = d0 * rstd * w[tid];
  float f1 = d1 * rstd * w[tid + 256];
  float f2 = d2 * rstd * w[tid + 512];
  outF[base + tid]       = (f16_t)f0;  outB[base + tid]       = (bf16_t)f0;
  outF[base + tid + 256] = (f16_t)f1;  outB[base + tid + 256] = (bf16_t)f1;
  outF[base + tid + 512] = (f16_t)f2;  outB[base + tid + 512] = (bf16_t)f2;

  // |p|^2 reduction of the Pi-side row
  const float* p = Pisrc + base;
  const float p0 = p[tid], p1 = p[tid + 256], p2 = p[tid + 512];
  __syncthreads();
  red[tid] = p0 * p0 + p1 * p1 + p2 * p2;
  __syncthreads();
  for (int off = 128; off > 0; off >>= 1) {
    if (tid < off) red[tid] += red[tid + off];
    __syncthreads();
  }
  if (tid == 0) {
    aab[row] = red[0];
    zbuf[row] = 0.0f;
  }
}

// Transpose Xnb [b][s][c] -> XT [b][c][s] (bf16). grid (Tn/64, Cn/64, Bn).
__global__ void __launch_bounds__(256) xt_kernel(
    const ushort* __restrict__ Xh, ushort* __restrict__ XT) {
  const int b = blockIdx.z;
  const int s0 = blockIdx.x * 64, c0 = blockIdx.y * 64;
  const int tid = threadIdx.x;
  __shared__ ushort t[64][68];
  const ushort* src = Xh + (size_t)b * Tn * Cn;
  ushort* dst = XT + (size_t)b * Cn * Tn;
  #pragma unroll
  for (int p = 0; p < 4; ++p) {
    const int r = p * 16 + (tid >> 4);
    const int c = (tid & 15) * 4;
    const ushort4 v = *(const ushort4*)&src[(size_t)(s0 + r) * Cn + c0 + c];
    *(ushort4*)&t[r][c] = v;
  }
  __syncthreads();
  #pragma unroll
  for (int p = 0; p < 4; ++p) {
    const int cc = p * 16 + (tid >> 4);
    const int ss = (tid & 15) * 4;
    ushort4 o;
    o.x = t[ss + 0][cc]; o.y = t[ss + 1][cc];
    o.z = t[ss + 2][cc]; o.w = t[ss + 3][cc];
    *(ushort4*)&dst[(size_t)(c0 + cc) * Tn + s0 + ss] = o;
  }
}

// Causal gram, 128x64 tile, single-fp16 MFMA, K=64 double-slab chunks.
// E = exp(clip(S*COEF)) stored single-bf16 into packed 128x128 triangular
// tiles (pair-packed uint stores). Row sums -> atomicAdd zbuf.
// grid = (272, Bn), block 256.
__global__ void __launch_bounds__(256) zpass_mfma(
    const f16_t* __restrict__ XnF,
    ushort* __restrict__ Ehp, float* __restrict__ zbuf) {
  const int b = blockIdx.y;
  const int l = blockIdx.x;
  int it = (int)(0.5f * (sqrtf(4.0f * (float)l + 1.0f) - 1.0f));
  while ((it + 1) * (it + 2) <= l) ++it;
  while (it * (it + 1) > l) --it;
  const int js = l - it * (it + 1);          // 0 .. 2it+1
  const int t0 = it * 128, s0 = js * 64;
  const int tri = it * (it + 1) / 2 + (js >> 1);
  const int colTileBase = (js & 1) * 64;

  const int tid  = threadIdx.x;
  const int lane = tid & 63;
  const int wv   = tid >> 6;
  const int wr   = wv >> 1, wc = wv & 1;     // wave covers 64t x 32s
  const int quad = lane >> 4, l15 = lane & 15;

  const f16_t* XbF = XnF + (size_t)b * Tn * Cn;
  ushort* EhT = Ehp + ((size_t)b * NTRI + tri) * 16384;

  __shared__ f16_t Af[2][128 * 32];   // 16 KB
  __shared__ f16_t Bf[2][64 * 32];    // 8 KB

  const int srow = lane >> 2;                // 0..15
  const int scol = (lane & 3) * 8;

  f32x4 acc[4][2] = {};

  for (int c0 = 0; c0 < Cn; c0 += 64) {
    __syncthreads();                 // protect LDS while prev chunk still read
    #pragma unroll
    for (int h = 0; h < 2; ++h) {
      const int cb = c0 + h * 32;
      const int rb0 = wv * 16, rb1 = 64 + wv * 16;
      gload16(XbF + (size_t)(t0 + rb0 + srow) * Cn + cb + scol, Af[h] + rb0 * 32);
      gload16(XbF + (size_t)(t0 + rb1 + srow) * Cn + cb + scol, Af[h] + rb1 * 32);
      gload16(XbF + (size_t)(s0 + rb0 + srow) * Cn + cb + scol, Bf[h] + rb0 * 32);
    }
    __syncthreads();                 // drain vmcnt + all slabs present

    #pragma unroll
    for (int h = 0; h < 2; ++h) {
      f16x8 af[4], bf[2];
      #pragma unroll
      for (int i = 0; i < 4; ++i)
        af[i] = *(const f16x8*)&Af[h][(wr * 64 + i * 16 + l15) * 32 + quad * 8];
      #pragma unroll
      for (int j = 0; j < 2; ++j)
        bf[j] = *(const f16x8*)&Bf[h][(wc * 32 + j * 16 + l15) * 32 + quad * 8];
      #pragma unroll
      for (int i = 0; i < 4; ++i)
        #pragma unroll
        for (int j = 0; j < 2; ++j)
          acc[i][j] = __builtin_amdgcn_mfma_f32_16x16x32_f16(af[i], bf[j], acc[i][j], 0, 0, 0);
    }
  }

  float zacc[4][4];
  #pragma unroll
  for (int i = 0; i < 4; ++i)
    #pragma unroll
    for (int r = 0; r < 4; ++r) zacc[i][r] = 0.0f;

  #pragma unroll
  for (int i = 0; i < 4; ++i) {
    #pragma unroll
    for (int j = 0; j < 2; ++j) {
      const int inCol = colTileBase + wc * 32 + j * 16 + l15;
      const int gcol  = s0 + wc * 32 + j * 16 + l15;
      #pragma unroll
      for (int r = 0; r < 4; ++r) {
        const int rowL = wr * 64 + i * 16 + quad * 4 + r;
        float sV = acc[i][j][r] * COEF;
        sV = fminf(fmaxf(sV, -60.f), 60.f);
        const float e = (gcol <= t0 + rowL) ? __expf(sV) : 0.f;
        const float pe = __shfl_xor(e, 1);
        if ((lane & 1) == 0) {
          const uint pk = (uint)bf16_bits(e) | ((uint)bf16_bits(pe) << 16);
          *(uint*)&EhT[rowL * 128 + inCol] = pk;
        }
        zacc[i][r] += e;
      }
    }
  }
  #pragma unroll
  for (int i = 0; i < 4; ++i)
    #pragma unroll
    for (int r = 0; r < 4; ++r) {
      float v = zacc[i][r];
      v += __shfl_xor(v, 1);
      v += __shfl_xor(v, 2);
      v += __shfl_xor(v, 4);
      v += __shfl_xor(v, 8);
      if (l15 == 0)
        atomicAdd(&zbuf[b * Tn + t0 + wr * 64 + i * 16 + quad * 4 + r], v);
    }
}

// Finalize z and sv elementwise over all Bn*Tn rows.
__global__ void __launch_bounds__(256) svfin_kernel(
    float* __restrict__ zbuf, float* __restrict__ sv,
    const float* __restrict__ aab, const float* __restrict__ cst, int ps_idx) {
  const int i = blockIdx.x * 256 + threadIdx.x;
  const float ps = cst[ps_idx];
  const float zf = fmaxf(zbuf[i] * (1.0f / Tn), EPSZ);
  zbuf[i] = zf;
  sv[i] = aab[i] * ps * ps / (zf * zf + EPSZ);
}

// XsT[b][c][s] = bf16( (sv[b][s]-2) * XT[b][c][s] ).
// grid (Cn, Bn); block 256 covers the full Tn row (8 ushorts/thread).
__global__ void __launch_bounds__(256) xs_kernel(
    const ushort* __restrict__ XT, ushort* __restrict__ XsT,
    const float* __restrict__ sv) {
  const int c = blockIdx.x, b = blockIdx.y;
  const int s8 = threadIdx.x * 8;
  const size_t base = ((size_t)b * Cn + c) * Tn + s8;
  const u16x8 x = *(const u16x8*)&XT[base];
  const float4 sa = *(const float4*)(sv + b * Tn + s8);
  const float4 sb = *(const float4*)(sv + b * Tn + s8 + 4);
  const float sw[8] = {sa.x, sa.y, sa.z, sa.w, sb.x, sb.y, sb.z, sb.w};
  u16x8 o;
  #pragma unroll
  for (int q = 0; q < 8; ++q)
    o[q] = bf16_bits(bits_to_f(x[q]) * (sw[q] - 2.0f));
  *(u16x8*)&XsT[base] = o;
}

// core GEMM (two accumulations vs same A=E) + fused elementwise epilogues.
// core = diag(sv_t) * (E @ X)  +  E @ (diag(sv_s - 2) * X)
// A = packed E tiles (async), B1 = XT, B2 = XsT (both async). Zero VALU in
// the K-loop. dst = src*cst[ss_idx] + coef*core, then per MODE.
// Tile 128t x 64c; 1D grid of 768 blocks, XCD-affinity swizzled so the 12
// c-blocks sharing an E strip land on the same XCD (id % 8 residue).
template <int MODE>
__global__ void __launch_bounds__(256) corepass_mfma(
    const ushort* __restrict__ Ehp, const ushort* __restrict__ XT,
    const ushort* __restrict__ XsT, const float* __restrict__ sv,
    const float* src, float* dst,
    const float* __restrict__ cst, int ss_idx, int lam_idx,
    float* eA, float* eB, float* eC, float* eD,
    const float* __restrict__ zb, int vel_idx, float rc, float rs) {
  // decode: id = r8 + 8*(g>>3) + 64*ic, g = (it<<2)|b
  const int id = blockIdx.x;
  const int r8 = id & 7;
  const int m  = id >> 3;
  const int g  = ((m & 7) << 3) | r8;
  const int ic = m >> 3;                 // 0..11
  const int it = g >> 2;                 // 0..15
  const int b  = g & 3;                  // 0..3
  const int t0 = it * 128, c0 = ic * 64;

  const int tid  = threadIdx.x;
  const int lane = tid & 63;
  const int wv   = tid >> 6;
  const int wr   = wv >> 1, wc = wv & 1;   // wave covers 64t x 32c
  const int quad = lane >> 4, l15 = lane & 15;

  const ushort* EhB  = Ehp + (size_t)b * NTRI * 16384;
  const ushort* XTb  = XT  + (size_t)b * Cn * Tn;
  const ushort* XsTb = XsT + (size_t)b * Cn * Tn;
  const float*  svB  = sv + b * Tn;

  __shared__ ushort Ah[2][128 * 32];   // E slabs   (16 KB)
  __shared__ ushort Bh[2][64 * 32];    // XT slabs  (8 KB)
  __shared__ ushort Bs[2][64 * 32];    // XsT slabs (8 KB)

  const int srow = lane >> 2;
  const int scol = (lane & 3) * 8;
  const int triBase = it * (it + 1) / 2;

  f32x4 acc1[4][2] = {};
  f32x4 acc2[4][2] = {};
  const int chunks = (it + 1) * 2;           // 64-k chunks
  for (int kc = 0; kc < chunks; ++kc) {
    const int ss0 = kc * 64;
    const int stile = kc >> 1, soff = (kc & 1) * 64;
    const ushort* tileB = EhB + (size_t)(triBase + stile) * 16384 + soff;

    __syncthreads();                 // prev chunk's LDS reads done
    #pragma unroll
    for (int h = 0; h < 2; ++h) {
      const ushort* tileH = tileB + h * 32;
      const int rb0 = wv * 16, rb1 = 64 + wv * 16;
      gload16(tileH + (size_t)(rb0 + srow) * 128 + scol, Ah[h] + rb0 * 32);
      gload16(tileH + (size_t)(rb1 + srow) * 128 + scol, Ah[h] + rb1 * 32);
      const size_t boff = (size_t)(c0 + wv * 16 + srow) * Tn + ss0 + h * 32 + scol;
      gload16(XTb  + boff, Bh[h] + wv * 16 * 32);
      gload16(XsTb + boff, Bs[h] + wv * 16 * 32);
    }
    __syncthreads();                 // drain vmcnt

    #pragma unroll
    for (int h = 0; h < 2; ++h) {
      bf16x8 ah[4], bh[2], bs2[2];
      #pragma unroll
      for (int i = 0; i < 4; ++i)
        ah[i] = *(const bf16x8*)&Ah[h][(wr * 64 + i * 16 + l15) * 32 + quad * 8];
      #pragma unroll
      for (int j = 0; j < 2; ++j) {
        bh[j]  = *(const bf16x8*)&Bh[h][(wc * 32 + j * 16 + l15) * 32 + quad * 8];
        bs2[j] = *(const bf16x8*)&Bs[h][(wc * 32 + j * 16 + l15) * 32 + quad * 8];
      }
      #pragma unroll
      for (int i = 0; i < 4; ++i)
        #pragma unroll
        for (int j = 0; j < 2; ++j) {
          acc1[i][j] = __builtin_amdgcn_mfma_f32_16x16x32_bf16(ah[i], bh[j],  acc1[i][j], 0, 0, 0);
          acc2[i][j] = __builtin_amdgcn_mfma_f32_16x16x32_bf16(ah[i], bs2[j], acc2[i][j], 0, 0, 0);
        }
    }
  }

  const float coef = 0.5f * cst[lam_idx] * (1.0f / (2.0f * Tn));
  const float ssc = cst[ss_idx];
  const float vs = 0.5f * cst[vel_idx];
  #pragma unroll
  for (int i = 0; i < 4; ++i) {
    float svr[4];
    #pragma unroll
    for (int r = 0; r < 4; ++r)
      svr[r] = svB[t0 + wr * 64 + i * 16 + quad * 4 + r];
    #pragma unroll
    for (int j = 0; j < 2; ++j) {
      const int col = c0 + wc * 32 + j * 16 + l15;
      #pragma unroll
      for (int r = 0; r < 4; ++r) {
        const int row = t0 + wr * 64 + i * 16 + quad * 4 + r;
        const size_t off = ((size_t)b * Tn + row) * Cn + col;
        const float srcv = src[off];
        const float core = svr[r] * acc1[i][j][r] + acc2[i][j][r];
        const float d = srcv * ssc + coef * core;
        if (MODE == 0) {
          dst[off] = d;
          eC[off] = eA[off] + vs * srcv / zb[b * Tn + row];
        } else if (MODE == 1) {
          const float z  = zb[b * Tn + row];
          const float po = eB[off];
          const float xo = eA[off] + vs * po / z;
          const float bx = eC[off];
          const float dX = xo - bx, dPi = po - d;
          const float sX = xo + bx, sPi = po + d;
          eD[off]  = 0.5f * (sX + rc * dX + rs * dPi);   // Xo
          eB[off]  = 0.5f * (sPi - rs * dX + rc * dPi);  // Po
          eC[off]  = 0.5f * (sX - rc * dX - rs * dPi);   // bX
          dst[off] = 0.5f * (sPi + rs * dX - rc * dPi);  // bPi
        } else if (MODE == 2) {
          dst[off] = d;
          eA[off] = eA[off] + vs * eB[off] / zb[b * Tn + row];
        } else {
          dst[off] = d;
        }
      }
    }
  }
}

// Final LayerNorm (fp32 out, in-place capable)
__global__ void __launch_bounds__(256) ln_f32_kernel(
    const float* src, const float* __restrict__ w,
    float* dst, const float* __restrict__ cst, int alpha_idx) {
  const int row = blockIdx.x;
  const int tid = threadIdx.x;
  const float alpha = cst[alpha_idx];
  const float* x = src + (size_t)row * Cn;
  float v0 = alpha * x[tid];
  float v1 = alpha * x[tid + 256];
  float v2 = alpha * x[tid + 512];
  __shared__ float red[256];
  red[tid] = v0 + v1 + v2;
  __syncthreads();
  for (int off = 128; off > 0; off >>= 1) {
    if (tid < off) red[tid] += red[tid + off];
    __syncthreads();
  }
  const float m = red[0] * (1.0f / Cn);
  __syncthreads();
  const float d0 = v0 - m, d1 = v1 - m, d2 = v2 - m;
  red[tid] = d0 * d0 + d1 * d1 + d2 * d2;
  __syncthreads();
  for (int off = 128; off > 0; off >>= 1) {
    if (tid < off) red[tid] += red[tid + off];
    __syncthreads();
  }
  const float rstd = rsqrtf(red[0] * (1.0f / Cn) + LNEPS);
  float* y = dst + (size_t)row * Cn;
  y[tid]       = d0 * rstd * w[tid];
  y[tid + 256] = d1 * rstd * w[tid + 256];
  y[tid + 512] = d2 * rstd * w[tid + 512];
}

extern "C" void kernel_launch(void* const* d_in, const int* in_sizes, int n_in,
                              void* d_out, int out_size, void* d_ws, size_t ws_size,
                              hipStream_t stream) {
  (void)in_sizes; (void)n_in; (void)out_size;
  const float* Xk  = (const float*)d_in[0];
  const float* Pk  = (const float*)d_in[1];
  const float* lw  = (const float*)d_in[2];
  const float* lvw = (const float*)d_in[3];
  const int*   kp  = (const int*)d_in[4];

  float* Xo = (float*)d_out;        // X state in d_out[0:BTC]
  float* Po = Xo + NBTC;            // Pi state in d_out[BTC:2BTC]

  char* wp = (char*)d_ws;
  float*  bX  = (float*)wp;  wp += NBTC * sizeof(float);
  float*  bPi = (float*)wp;  wp += NBTC * sizeof(float);
  f16_t*  XnF = (f16_t*)wp;  wp += NBTC * sizeof(f16_t);
  bf16_t* Xnb = (bf16_t*)wp; wp += NBTC * sizeof(bf16_t);
  ushort* Ehp = (ushort*)wp; wp += (size_t)Bn * NTRI * 16384 * sizeof(ushort);
  ushort* XTh = (ushort*)wp; wp += NBTC * sizeof(ushort);
  ushort* XsT = (ushort*)wp; wp += NBTC * sizeof(ushort);
  float*  zb  = (float*)wp;  wp += (size_t)Bn * Tn * sizeof(float);
  float*  sv  = (float*)wp;  wp += (size_t)Bn * Tn * sizeof(float);
  float*  aab = (float*)wp;  wp += (size_t)Bn * Tn * sizeof(float);
  float*  cst = (float*)wp;  wp += 256;
  const size_t need = (size_t)(wp - (char*)d_ws);
  if (ws_size < need) {
    fprintf(stderr, "[kernel] ws too small: %zu < %zu\n", ws_size, need);
    return;
  }

  const dim3 b256(256);
  const dim3 gLN(Bn * Tn);
  const dim3 gXT(Tn / 64, Cn / 64, Bn);      // (32,12,4)
  const dim3 gZ(272, Bn);                    // causal 128x64 tiles x batch
  const dim3 gSV(Bn * Tn / 256);             // 32 blocks
  const dim3 gXS(Cn, Bn);                    // xs scale kernel
  const dim3 gCore(768);                     // XCD-swizzled 1D grid
  const float rc = (float)cos(2.0), rs = (float)sin(2.0);   // theta = 2*XI*h

  prep_consts<<<1, 1, 0, stream>>>(kp, cst);

  // ---- Stage A: X-side = Xk, p = Pk (lam*Lam = 1) ----
  ln_sv_kernel<<<gLN, b256, 0, stream>>>(Xk, lw, XnF, Xnb, zb, aab, Pk, cst, 6);
  xt_kernel<<<gXT, b256, 0, stream>>>((const ushort*)Xnb, XTh);
  zpass_mfma<<<gZ, b256, 0, stream>>>(XnF, Ehp, zb);
  svfin_kernel<<<gSV, b256, 0, stream>>>(zb, sv, aab, cst, 6);
  xs_kernel<<<gXS, b256, 0, stream>>>(XTh, XsT, sv);
  corepass_mfma<0><<<gCore, b256, 0, stream>>>(Ehp, XTh, XsT, sv, Pk, Po, cst, 0, 0,
      (float*)Xk, nullptr, bX, nullptr, zb, 6, rc, rs);

  // ---- Stage B: X-side = bX, Pi-side = Po; fused velupd-B + rotation ----
  ln_sv_kernel<<<gLN, b256, 0, stream>>>(bX, lw, XnF, Xnb, zb, aab, Po, cst, 6);
  xt_kernel<<<gXT, b256, 0, stream>>>((const ushort*)Xnb, XTh);
  zpass_mfma<<<gZ, b256, 0, stream>>>(XnF, Ehp, zb);
  svfin_kernel<<<gSV, b256, 0, stream>>>(zb, sv, aab, cst, 3);
  xs_kernel<<<gXS, b256, 0, stream>>>(XTh, XsT, sv);
  corepass_mfma<1><<<gCore, b256, 0, stream>>>(Ehp, XTh, XsT, sv, Pk, bPi, cst, 0, 2,
      (float*)Xk, Po, bX, Xo, zb, 3, rc, rs);

  // ---- Stage C: X-side = bX, Pi-side = Po; fused velupd-C ----
  ln_sv_kernel<<<gLN, b256, 0, stream>>>(bX, lw, XnF, Xnb, zb, aab, Po, cst, 6);
  xt_kernel<<<gXT, b256, 0, stream>>>((const ushort*)Xnb, XTh);
  zpass_mfma<<<gZ, b256, 0, stream>>>(XnF, Ehp, zb);
  svfin_kernel<<<gSV, b256, 0, stream>>>(zb, sv, aab, cst, 3);
  xs_kernel<<<gXS, b256, 0, stream>>>(XTh, XsT, sv);
  corepass_mfma<2><<<gCore, b256, 0, stream>>>(Ehp, XTh, XsT, sv, bPi, bPi, cst, 6, 2,
      Xo, Po, nullptr, nullptr, zb, 3, rc, rs);

  // ---- Stage D: X-side = Xo, p = lam_tk1*bPi ----
  ln_sv_kernel<<<gLN, b256, 0, stream>>>(Xo, lw, XnF, Xnb, zb, aab, bPi, cst, 6);
  xt_kernel<<<gXT, b256, 0, stream>>>((const ushort*)Xnb, XTh);
  zpass_mfma<<<gZ, b256, 0, stream>>>(XnF, Ehp, zb);
  svfin_kernel<<<gSV, b256, 0, stream>>>(zb, sv, aab, cst, 5);
  xs_kernel<<<gXS, b256, 0, stream>>>(XTh, XsT, sv);
  corepass_mfma<3><<<gCore, b256, 0, stream>>>(Ehp, XTh, XsT, sv, Po, Po, cst, 6, 4,
      nullptr, nullptr, nullptr, nullptr, zb, 6, rc, rs);

  // ---- Final: Pk1 = LN(lam_tk1 * Pi) * ln_v_w (in place on Po) ----
  ln_f32_kernel<<<gLN, b256, 0, stream>>>(Po, lvw, Po, cst, 5);
}

// Round 11
// 640.017 us; speedup vs baseline: 1.1215x; 1.0824x over previous
//
#include <hip/hip_runtime.h>
#include <hip/hip_bf16.h>
#include <cstdio>
#include <cmath>

// Problem constants (B,T,C,NH fixed by the reference)
constexpr int   Bn = 4;
constexpr int   Tn = 2048;
constexpr int   Cn = 768;
constexpr float COEF  = 0.125f / 12.0f;   // SCALE / NH
constexpr float EPSZ  = 1e-8f;
constexpr float LNEPS = 1e-5f;
constexpr int   NTRI  = 136;              // triangular 128-tiles per batch
#define NBTC ((size_t)Bn * Tn * Cn)

typedef __bf16 bf16_t;
typedef _Float16 f16_t;
typedef bf16_t bf16x8 __attribute__((ext_vector_type(8)));
typedef f16_t  f16x8  __attribute__((ext_vector_type(8)));
typedef float  f32x4  __attribute__((ext_vector_type(4)));
typedef ushort u16x8  __attribute__((ext_vector_type(8)));

// async global->LDS, 16B per lane. LDS dest is wave-uniform base + lane*16.
__device__ __forceinline__ void gload16(const void* g, void* l) {
  __builtin_amdgcn_global_load_lds(
      (const __attribute__((address_space(1))) unsigned int*)g,
      (__attribute__((address_space(3))) unsigned int*)l,
      16, 0, 0);
}

__device__ __forceinline__ ushort bf16_bits(float f) {
  bf16_t h = (bf16_t)f;
  return __builtin_bit_cast(ushort, h);
}
__device__ __forceinline__ float bits_to_f(ushort u) {
  return (float)__builtin_bit_cast(bf16_t, u);
}

// cst[] indices: 0 Lam_tk, 1 lam_tk, 2 Lam_tbar, 3 lam_tbar, 4 Lam_tk1, 5 lam_tk1, 6 = 1.0
__global__ void prep_consts(const int* kp, float* cst) {
  if (threadIdx.x == 0 && blockIdx.x == 0) {
    float tk = 1.0f + (float)(*kp);
    float tb = tk + 0.5f;
    float t1 = tk + 1.0f;
    cst[0] = tk * tk * tk; cst[1] = 1.0f / cst[0];
    cst[2] = tb * tb * tb; cst[3] = 1.0f / cst[2];
    cst[4] = t1 * t1 * t1; cst[5] = 1.0f / cst[4];
    cst[6] = 1.0f;
  }
}

// LayerNorm of (alpha*src) -> fp16 (gram) + bf16 (corepass) outputs, PLUS
// |Pi row|^2 reduction -> aab[row]. Also zeroes zbuf[row] for zpass atomics.
__global__ void __launch_bounds__(256) ln_sv_kernel(
    const float* __restrict__ src, const float* __restrict__ w,
    f16_t* __restrict__ outF, bf16_t* __restrict__ outB,
    float* __restrict__ zbuf, float* __restrict__ aab,
    const float* __restrict__ Pisrc,
    const float* __restrict__ cst, int alpha_idx) {
  const int row = blockIdx.x;
  const int tid = threadIdx.x;
  const float alpha = cst[alpha_idx];
  const float* x = src + (size_t)row * Cn;
  float v0 = alpha * x[tid];
  float v1 = alpha * x[tid + 256];
  float v2 = alpha * x[tid + 512];
  __shared__ float red[256];
  red[tid] = v0 + v1 + v2;
  __syncthreads();
  for (int off = 128; off > 0; off >>= 1) {
    if (tid < off) red[tid] += red[tid + off];
    __syncthreads();
  }
  const float m = red[0] * (1.0f / Cn);
  __syncthreads();
  const float d0 = v0 - m, d1 = v1 - m, d2 = v2 - m;
  red[tid] = d0 * d0 + d1 * d1 + d2 * d2;
  __syncthreads();
  for (int off = 128; off > 0; off >>= 1) {
    if (tid < off) red[tid] += red[tid + off];
    __syncthreads();
  }
  const float rstd = rsqrtf(red[0] * (1.0f / Cn) + LNEPS);
  const size_t base = (size_t)row * Cn;
  float f0 = d0 * rstd * w[tid];
  float f1 = d1 * rstd * w[tid + 256];
  float f2 = d2 * rstd * w[tid + 512];
  outF[base + tid]       = (f16_t)f0;  outB[base + tid]       = (bf16_t)f0;
  outF[base + tid + 256] = (f16_t)f1;  outB[base + tid + 256] = (bf16_t)f1;
  outF[base + tid + 512] = (f16_t)f2;  outB[base + tid + 512] = (bf16_t)f2;

  // |p|^2 reduction of the Pi-side row
  const float* p = Pisrc + base;
  const float p0 = p[tid], p1 = p[tid + 256], p2 = p[tid + 512];
  __syncthreads();
  red[tid] = p0 * p0 + p1 * p1 + p2 * p2;
  __syncthreads();
  for (int off = 128; off > 0; off >>= 1) {
    if (tid < off) red[tid] += red[tid + off];
    __syncthreads();
  }
  if (tid == 0) {
    aab[row] = red[0];
    zbuf[row] = 0.0f;
  }
}

// Transpose Xnb [b][s][c] -> XT [b][c][s] (bf16). grid (Tn/64, Cn/64, Bn).
__global__ void __launch_bounds__(256) xt_kernel(
    const ushort* __restrict__ Xh, ushort* __restrict__ XT) {
  const int b = blockIdx.z;
  const int s0 = blockIdx.x * 64, c0 = blockIdx.y * 64;
  const int tid = threadIdx.x;
  __shared__ ushort t[64][68];
  const ushort* src = Xh + (size_t)b * Tn * Cn;
  ushort* dst = XT + (size_t)b * Cn * Tn;
  #pragma unroll
  for (int p = 0; p < 4; ++p) {
    const int r = p * 16 + (tid >> 4);
    const int c = (tid & 15) * 4;
    const ushort4 v = *(const ushort4*)&src[(size_t)(s0 + r) * Cn + c0 + c];
    *(ushort4*)&t[r][c] = v;
  }
  __syncthreads();
  #pragma unroll
  for (int p = 0; p < 4; ++p) {
    const int cc = p * 16 + (tid >> 4);
    const int ss = (tid & 15) * 4;
    ushort4 o;
    o.x = t[ss + 0][cc]; o.y = t[ss + 1][cc];
    o.z = t[ss + 2][cc]; o.w = t[ss + 3][cc];
    *(ushort4*)&dst[(size_t)(c0 + cc) * Tn + s0 + ss] = o;
  }
}

// Causal gram, 128x64 tile, single-fp16 MFMA, K=64 double-slab chunks.
// E = exp(clip(S*COEF)) stored single-bf16 into packed 128x128 triangular
// tiles (pair-packed uint stores). Row sums -> atomicAdd zbuf.
// grid = (272, Bn), block 256.
__global__ void __launch_bounds__(256) zpass_mfma(
    const f16_t* __restrict__ XnF,
    ushort* __restrict__ Ehp, float* __restrict__ zbuf) {
  const int b = blockIdx.y;
  const int l = blockIdx.x;
  int it = (int)(0.5f * (sqrtf(4.0f * (float)l + 1.0f) - 1.0f));
  while ((it + 1) * (it + 2) <= l) ++it;
  while (it * (it + 1) > l) --it;
  const int js = l - it * (it + 1);          // 0 .. 2it+1
  const int t0 = it * 128, s0 = js * 64;
  const int tri = it * (it + 1) / 2 + (js >> 1);
  const int colTileBase = (js & 1) * 64;

  const int tid  = threadIdx.x;
  const int lane = tid & 63;
  const int wv   = tid >> 6;
  const int wr   = wv >> 1, wc = wv & 1;     // wave covers 64t x 32s
  const int quad = lane >> 4, l15 = lane & 15;

  const f16_t* XbF = XnF + (size_t)b * Tn * Cn;
  ushort* EhT = Ehp + ((size_t)b * NTRI + tri) * 16384;

  __shared__ f16_t Af[2][128 * 32];   // 16 KB
  __shared__ f16_t Bf[2][64 * 32];    // 8 KB

  const int srow = lane >> 2;                // 0..15
  const int scol = (lane & 3) * 8;

  f32x4 acc[4][2] = {};

  for (int c0 = 0; c0 < Cn; c0 += 64) {
    __syncthreads();                 // protect LDS while prev chunk still read
    #pragma unroll
    for (int h = 0; h < 2; ++h) {
      const int cb = c0 + h * 32;
      const int rb0 = wv * 16, rb1 = 64 + wv * 16;
      gload16(XbF + (size_t)(t0 + rb0 + srow) * Cn + cb + scol, Af[h] + rb0 * 32);
      gload16(XbF + (size_t)(t0 + rb1 + srow) * Cn + cb + scol, Af[h] + rb1 * 32);
      gload16(XbF + (size_t)(s0 + rb0 + srow) * Cn + cb + scol, Bf[h] + rb0 * 32);
    }
    __syncthreads();                 // drain vmcnt + all slabs present

    #pragma unroll
    for (int h = 0; h < 2; ++h) {
      f16x8 af[4], bf[2];
      #pragma unroll
      for (int i = 0; i < 4; ++i)
        af[i] = *(const f16x8*)&Af[h][(wr * 64 + i * 16 + l15) * 32 + quad * 8];
      #pragma unroll
      for (int j = 0; j < 2; ++j)
        bf[j] = *(const f16x8*)&Bf[h][(wc * 32 + j * 16 + l15) * 32 + quad * 8];
      #pragma unroll
      for (int i = 0; i < 4; ++i)
        #pragma unroll
        for (int j = 0; j < 2; ++j)
          acc[i][j] = __builtin_amdgcn_mfma_f32_16x16x32_f16(af[i], bf[j], acc[i][j], 0, 0, 0);
    }
  }

  float zacc[4][4];
  #pragma unroll
  for (int i = 0; i < 4; ++i)
    #pragma unroll
    for (int r = 0; r < 4; ++r) zacc[i][r] = 0.0f;

  #pragma unroll
  for (int i = 0; i < 4; ++i) {
    #pragma unroll
    for (int j = 0; j < 2; ++j) {
      const int inCol = colTileBase + wc * 32 + j * 16 + l15;
      const int gcol  = s0 + wc * 32 + j * 16 + l15;
      #pragma unroll
      for (int r = 0; r < 4; ++r) {
        const int rowL = wr * 64 + i * 16 + quad * 4 + r;
        float sV = acc[i][j][r] * COEF;
        sV = fminf(fmaxf(sV, -60.f), 60.f);
        const float e = (gcol <= t0 + rowL) ? __expf(sV) : 0.f;
        const float pe = __shfl_xor(e, 1);
        if ((lane & 1) == 0) {
          const uint pk = (uint)bf16_bits(e) | ((uint)bf16_bits(pe) << 16);
          *(uint*)&EhT[rowL * 128 + inCol] = pk;
        }
        zacc[i][r] += e;
      }
    }
  }
  #pragma unroll
  for (int i = 0; i < 4; ++i)
    #pragma unroll
    for (int r = 0; r < 4; ++r) {
      float v = zacc[i][r];
      v += __shfl_xor(v, 1);
      v += __shfl_xor(v, 2);
      v += __shfl_xor(v, 4);
      v += __shfl_xor(v, 8);
      if (l15 == 0)
        atomicAdd(&zbuf[b * Tn + t0 + wr * 64 + i * 16 + quad * 4 + r], v);
    }
}

// Finalize z and sv elementwise over all Bn*Tn rows.
__global__ void __launch_bounds__(256) svfin_kernel(
    float* __restrict__ zbuf, float* __restrict__ sv,
    const float* __restrict__ aab, const float* __restrict__ cst, int ps_idx) {
  const int i = blockIdx.x * 256 + threadIdx.x;
  const float ps = cst[ps_idx];
  const float zf = fmaxf(zbuf[i] * (1.0f / Tn), EPSZ);
  zbuf[i] = zf;
  sv[i] = aab[i] * ps * ps / (zf * zf + EPSZ);
}

// In-place W-build: E[t,s] *= (sv[t] + sv[s] - 2), packed single-bf16 tiles.
// grid = (16 s-tiles, 16 t-tiles, Bn); skip strictly-upper tiles.
__global__ void __launch_bounds__(256) wbuild_kernel(
    ushort* __restrict__ Ehp, const float* __restrict__ sv) {
  const int st = blockIdx.x, it = blockIdx.y, b = blockIdx.z;
  if (st > it) return;
  const int tri = it * (it + 1) / 2 + st;
  ushort* EhT = Ehp + ((size_t)b * NTRI + tri) * 16384;
  const float* svB = sv + b * Tn;

  const int tid = threadIdx.x;
  const int r  = tid >> 1;            // 0..127
  const int ch = (tid & 1) * 64;      // col half
  const float svt2 = svB[it * 128 + r] - 2.0f;
  const int base = r * 128 + ch;
  #pragma unroll
  for (int v = 0; v < 8; ++v) {
    u16x8 h8 = *(const u16x8*)&EhT[base + v * 8];
    const float4 sa = *(const float4*)(svB + st * 128 + ch + v * 8);
    const float4 sb = *(const float4*)(svB + st * 128 + ch + v * 8 + 4);
    const float ss[8] = {sa.x, sa.y, sa.z, sa.w, sb.x, sb.y, sb.z, sb.w};
    u16x8 nh;
    #pragma unroll
    for (int q = 0; q < 8; ++q) {
      const float w = bits_to_f(h8[q]) * (svt2 + ss[q]);
      nh[q] = bf16_bits(w);
    }
    *(u16x8*)&EhT[base + v * 8] = nh;
  }
}

// core GEMM + fused elementwise epilogues. K=64 double-slab chunks.
// dst = src*cst[ss_idx] + coef * W @ Xn, then per MODE (see launches).
// Tile 128t x 64c; 1D grid of 768 blocks. Swizzle: ic-siblings share id%8
// (same XCD -> W strip fetched into one L2) AND it descends as id ascends
// within each 64-block band (big-K first -> light tail).
template <int MODE>
__global__ void __launch_bounds__(256) corepass_mfma(
    const ushort* __restrict__ Whp, const ushort* __restrict__ XT,
    const float* src, float* dst,
    const float* __restrict__ cst, int ss_idx, int lam_idx,
    float* eA, float* eB, float* eC, float* eD,
    const float* __restrict__ zb, int vel_idx, float rc, float rs) {
  // encode: id = lo + 8*(7-hi) + 64*ic, hi=it>>1, lo=((it&1)<<2)|b
  const int id = blockIdx.x;
  const int lo = id & 7;
  const int q8 = (id >> 3) & 7;
  const int ic = id >> 6;                // 0..11
  const int it = ((7 - q8) << 1) | (lo >> 2);   // 15,14 first
  const int b  = lo & 3;
  const int t0 = it * 128, c0 = ic * 64;

  const int tid  = threadIdx.x;
  const int lane = tid & 63;
  const int wv   = tid >> 6;
  const int wr   = wv >> 1, wc = wv & 1;   // wave covers 64t x 32c
  const int quad = lane >> 4, l15 = lane & 15;

  const ushort* WhB = Whp + (size_t)b * NTRI * 16384;
  const ushort* XTb = XT + (size_t)b * Cn * Tn;

  __shared__ ushort Ah[2][128 * 32];   // W slabs  (16 KB)
  __shared__ ushort Bh[2][64 * 32];    // X^T slabs (8 KB)

  const int srow = lane >> 2;
  const int scol = (lane & 3) * 8;
  const int triBase = it * (it + 1) / 2;

  f32x4 acc[4][2] = {};
  const int chunks = (it + 1) * 2;           // 64-k chunks
  for (int kc = 0; kc < chunks; ++kc) {
    const int ss0 = kc * 64;
    const int stile = kc >> 1, soff = (kc & 1) * 64;
    const ushort* tileB = WhB + (size_t)(triBase + stile) * 16384 + soff;

    __syncthreads();                 // prev chunk's LDS reads done
    #pragma unroll
    for (int h = 0; h < 2; ++h) {
      const ushort* tileH = tileB + h * 32;
      const int rb0 = wv * 16, rb1 = 64 + wv * 16;
      gload16(tileH + (size_t)(rb0 + srow) * 128 + scol, Ah[h] + rb0 * 32);
      gload16(tileH + (size_t)(rb1 + srow) * 128 + scol, Ah[h] + rb1 * 32);
      gload16(XTb + (size_t)(c0 + wv * 16 + srow) * Tn + ss0 + h * 32 + scol,
              Bh[h] + wv * 16 * 32);
    }
    __syncthreads();                 // drain vmcnt

    #pragma unroll
    for (int h = 0; h < 2; ++h) {
      bf16x8 ah[4], bh[2];
      #pragma unroll
      for (int i = 0; i < 4; ++i)
        ah[i] = *(const bf16x8*)&Ah[h][(wr * 64 + i * 16 + l15) * 32 + quad * 8];
      #pragma unroll
      for (int j = 0; j < 2; ++j)
        bh[j] = *(const bf16x8*)&Bh[h][(wc * 32 + j * 16 + l15) * 32 + quad * 8];
      #pragma unroll
      for (int i = 0; i < 4; ++i)
        #pragma unroll
        for (int j = 0; j < 2; ++j)
          acc[i][j] = __builtin_amdgcn_mfma_f32_16x16x32_bf16(ah[i], bh[j], acc[i][j], 0, 0, 0);
    }
  }

  const float coef = 0.5f * cst[lam_idx] * (1.0f / (2.0f * Tn));
  const float ssc = cst[ss_idx];
  const float vs = 0.5f * cst[vel_idx];
  #pragma unroll
  for (int i = 0; i < 4; ++i) {
    #pragma unroll
    for (int j = 0; j < 2; ++j) {
      const int col = c0 + wc * 32 + j * 16 + l15;
      #pragma unroll
      for (int r = 0; r < 4; ++r) {
        const int row = t0 + wr * 64 + i * 16 + quad * 4 + r;
        const size_t off = ((size_t)b * Tn + row) * Cn + col;
        const float srcv = src[off];
        const float d = srcv * ssc + coef * acc[i][j][r];
        if (MODE == 0) {
          dst[off] = d;
          eC[off] = eA[off] + vs * srcv / zb[b * Tn + row];
        } else if (MODE == 1) {
          const float z  = zb[b * Tn + row];
          const float po = eB[off];
          const float xo = eA[off] + vs * po / z;
          const float bx = eC[off];
          const float dX = xo - bx, dPi = po - d;
          const float sX = xo + bx, sPi = po + d;
          eD[off]  = 0.5f * (sX + rc * dX + rs * dPi);   // Xo
          eB[off]  = 0.5f * (sPi - rs * dX + rc * dPi);  // Po
          eC[off]  = 0.5f * (sX - rc * dX - rs * dPi);   // bX
          dst[off] = 0.5f * (sPi + rs * dX - rc * dPi);  // bPi
        } else if (MODE == 2) {
          dst[off] = d;
          eA[off] = eA[off] + vs * eB[off] / zb[b * Tn + row];
        } else {
          dst[off] = d;
        }
      }
    }
  }
}

// Final LayerNorm (fp32 out, in-place capable)
__global__ void __launch_bounds__(256) ln_f32_kernel(
    const float* src, const float* __restrict__ w,
    float* dst, const float* __restrict__ cst, int alpha_idx) {
  const int row = blockIdx.x;
  const int tid = threadIdx.x;
  const float alpha = cst[alpha_idx];
  const float* x = src + (size_t)row * Cn;
  float v0 = alpha * x[tid];
  float v1 = alpha * x[tid + 256];
  float v2 = alpha * x[tid + 512];
  __shared__ float red[256];
  red[tid] = v0 + v1 + v2;
  __syncthreads();
  for (int off = 128; off > 0; off >>= 1) {
    if (tid < off) red[tid] += red[tid + off];
    __syncthreads();
  }
  const float m = red[0] * (1.0f / Cn);
  __syncthreads();
  const float d0 = v0 - m, d1 = v1 - m, d2 = v2 - m;
  red[tid] = d0 * d0 + d1 * d1 + d2 * d2;
  __syncthreads();
  for (int off = 128; off > 0; off >>= 1) {
    if (tid < off) red[tid] += red[tid + off];
    __syncthreads();
  }
  const float rstd = rsqrtf(red[0] * (1.0f / Cn) + LNEPS);
  float* y = dst + (size_t)row * Cn;
  y[tid]       = d0 * rstd * w[tid];
  y[tid + 256] = d1 * rstd * w[tid + 256];
  y[tid + 512] = d2 * rstd * w[tid + 512];
}

extern "C" void kernel_launch(void* const* d_in, const int* in_sizes, int n_in,
                              void* d_out, int out_size, void* d_ws, size_t ws_size,
                              hipStream_t stream) {
  (void)in_sizes; (void)n_in; (void)out_size;
  const float* Xk  = (const float*)d_in[0];
  const float* Pk  = (const float*)d_in[1];
  const float* lw  = (const float*)d_in[2];
  const float* lvw = (const float*)d_in[3];
  const int*   kp  = (const int*)d_in[4];

  float* Xo = (float*)d_out;        // X state in d_out[0:BTC]
  float* Po = Xo + NBTC;            // Pi state in d_out[BTC:2BTC]

  char* wp = (char*)d_ws;
  float*  bX  = (float*)wp;  wp += NBTC * sizeof(float);
  float*  bPi = (float*)wp;  wp += NBTC * sizeof(float);
  f16_t*  XnF = (f16_t*)wp;  wp += NBTC * sizeof(f16_t);
  bf16_t* Xnb = (bf16_t*)wp; wp += NBTC * sizeof(bf16_t);
  ushort* Ehp = (ushort*)wp; wp += (size_t)Bn * NTRI * 16384 * sizeof(ushort);
  ushort* XTh = (ushort*)wp; wp += NBTC * sizeof(ushort);
  float*  zb  = (float*)wp;  wp += (size_t)Bn * Tn * sizeof(float);
  float*  sv  = (float*)wp;  wp += (size_t)Bn * Tn * sizeof(float);
  float*  aab = (float*)wp;  wp += (size_t)Bn * Tn * sizeof(float);
  float*  cst = (float*)wp;  wp += 256;
  const size_t need = (size_t)(wp - (char*)d_ws);
  if (ws_size < need) {
    fprintf(stderr, "[kernel] ws too small: %zu < %zu\n", ws_size, need);
    return;
  }

  const dim3 b256(256);
  const dim3 gLN(Bn * Tn);
  const dim3 gXT(Tn / 64, Cn / 64, Bn);      // (32,12,4)
  const dim3 gZ(272, Bn);                    // causal 128x64 tiles x batch
  const dim3 gSV(Bn * Tn / 256);             // 32 blocks
  const dim3 gW(16, 16, Bn);                 // wbuild (skips upper)
  const dim3 gCore(768);                     // XCD-swizzled, big-K-first
  const float rc = (float)cos(2.0), rs = (float)sin(2.0);   // theta = 2*XI*h

  prep_consts<<<1, 1, 0, stream>>>(kp, cst);

  // ---- Stage A: X-side = Xk, p = Pk (lam*Lam = 1) ----
  ln_sv_kernel<<<gLN, b256, 0, stream>>>(Xk, lw, XnF, Xnb, zb, aab, Pk, cst, 6);
  xt_kernel<<<gXT, b256, 0, stream>>>((const ushort*)Xnb, XTh);
  zpass_mfma<<<gZ, b256, 0, stream>>>(XnF, Ehp, zb);
  svfin_kernel<<<gSV, b256, 0, stream>>>(zb, sv, aab, cst, 6);
  wbuild_kernel<<<gW, b256, 0, stream>>>(Ehp, sv);
  corepass_mfma<0><<<gCore, b256, 0, stream>>>(Ehp, XTh, Pk, Po, cst, 0, 0,
      (float*)Xk, nullptr, bX, nullptr, zb, 6, rc, rs);

  // ---- Stage B: X-side = bX, Pi-side = Po; fused velupd-B + rotation ----
  ln_sv_kernel<<<gLN, b256, 0, stream>>>(bX, lw, XnF, Xnb, zb, aab, Po, cst, 6);
  xt_kernel<<<gXT, b256, 0, stream>>>((const ushort*)Xnb, XTh);
  zpass_mfma<<<gZ, b256, 0, stream>>>(XnF, Ehp, zb);
  svfin_kernel<<<gSV, b256, 0, stream>>>(zb, sv, aab, cst, 3);
  wbuild_kernel<<<gW, b256, 0, stream>>>(Ehp, sv);
  corepass_mfma<1><<<gCore, b256, 0, stream>>>(Ehp, XTh, Pk, bPi, cst, 0, 2,
      (float*)Xk, Po, bX, Xo, zb, 3, rc, rs);

  // ---- Stage C: X-side = bX, Pi-side = Po; fused velupd-C ----
  ln_sv_kernel<<<gLN, b256, 0, stream>>>(bX, lw, XnF, Xnb, zb, aab, Po, cst, 6);
  xt_kernel<<<gXT, b256, 0, stream>>>((const ushort*)Xnb, XTh);
  zpass_mfma<<<gZ, b256, 0, stream>>>(XnF, Ehp, zb);
  svfin_kernel<<<gSV, b256, 0, stream>>>(zb, sv, aab, cst, 3);
  wbuild_kernel<<<gW, b256, 0, stream>>>(Ehp, sv);
  corepass_mfma<2><<<gCore, b256, 0, stream>>>(Ehp, XTh, bPi, bPi, cst, 6, 2,
      Xo, Po, nullptr, nullptr, zb, 3, rc, rs);

  // ---- Stage D: X-side = Xo, p = lam_tk1*bPi ----
  ln_sv_kernel<<<gLN, b256, 0, stream>>>(Xo, lw, XnF, Xnb, zb, aab, bPi, cst, 6);
  xt_kernel<<<gXT, b256, 0, stream>>>((const ushort*)Xnb, XTh);
  zpass_mfma<<<gZ, b256, 0, stream>>>(XnF, Ehp, zb);
  svfin_kernel<<<gSV, b256, 0, stream>>>(zb, sv, aab, cst, 5);
  wbuild_kernel<<<gW, b256, 0, stream>>>(Ehp, sv);
  corepass_mfma<3><<<gCore, b256, 0, stream>>>(Ehp, XTh, Po, Po, cst, 6, 4,
      nullptr, nullptr, nullptr, nullptr, zb, 6, rc, rs);

  // ---- Final: Pk1 = LN(lam_tk1 * Pi) * ln_v_w (in place on Po) ----
  ln_f32_kernel<<<gLN, b256, 0, stream>>>(Po, lvw, Po, cst, 5);
}